// Round 2
// baseline (3207.252 us; speedup 1.0000x reference)
//
#include <hip/hip_runtime.h>
#include <hip/hip_bf16.h>

// Problem dims: V=32000, E=H=256, L=2, B=32, S=64, S_ENC=64, 2H=512, 3H=768
// All real tensors are float32 on device (harness follows reference dtypes).

typedef _Float16 h2v __attribute__((ext_vector_type(2)));
typedef _Float16 f16x8 __attribute__((ext_vector_type(8)));
typedef float f32x4 __attribute__((ext_vector_type(4)));

__device__ inline float sigmf(float x) { return 1.f / (1.f + __expf(-x)); }
__device__ inline float tanhfast(float x) { return 2.f / (1.f + __expf(-2.f * x)) - 1.f; }

__device__ inline float dot2acc(unsigned a, unsigned b, float c) {
#if __has_builtin(__builtin_amdgcn_fdot2)
  return __builtin_amdgcn_fdot2(__builtin_bit_cast(h2v, a), __builtin_bit_cast(h2v, b), c, false);
#else
  h2v av = __builtin_bit_cast(h2v, a), bv = __builtin_bit_cast(h2v, b);
  return c + (float)av.x * (float)bv.x + (float)av.y * (float)bv.y;
#endif
}

// dot of n8*8 f16 elements; w global, h LDS/generic. 16B vector loads both sides.
__device__ inline float dotf16(const _Float16* __restrict__ w, const _Float16* h, int n8) {
  const uint4* wp = (const uint4*)w;
  const uint4* hp = (const uint4*)h;
  float acc = 0.f;
#pragma unroll 4
  for (int i = 0; i < n8; i++) {
    uint4 a = wp[i];
    uint4 b = hp[i];
    acc = dot2acc(a.x, b.x, acc);
    acc = dot2acc(a.y, b.y, acc);
    acc = dot2acc(a.z, b.z, acc);
    acc = dot2acc(a.w, b.w, acc);
  }
  return acc;
}

// ---------------- K0: f32 -> f16 convert ----------------
__global__ void k_cvt(const float* __restrict__ s, _Float16* __restrict__ d, int n) {
  int i = blockIdx.x * blockDim.x + threadIdx.x;
  int stride = gridDim.x * blockDim.x;
  for (; i < n; i += stride) d[i] = (_Float16)s[i];
}

// ---------------- K1: gi0[t,b,:] = relu(emb[tok]) @ Wih0^T + bih0 ----------------
__global__ __launch_bounds__(256) void k_gi0(const int* __restrict__ ow,
                                             const float* __restrict__ emb,
                                             const _Float16* __restrict__ Wih0f,
                                             const float* __restrict__ b_ih,
                                             float* __restrict__ gi0) {
  __shared__ __align__(16) _Float16 x[256];
  int m = blockIdx.x;            // m = t*32 + b
  int b = m & 31, t = m >> 5;
  int tid = threadIdx.x;
  int tok = ow[b * 65 + t];      // teacher forcing uses output_words[:, :-1]
  x[tid] = (_Float16)fmaxf(emb[(size_t)tok * 256 + tid], 0.f);
  __syncthreads();
#pragma unroll
  for (int p = 0; p < 3; p++) {
    int j = tid + p * 256;
    gi0[(size_t)m * 768 + j] = dotf16(Wih0f + (size_t)j * 256, x, 32) + b_ih[j];
  }
}

// ---------------- K2: sequential GRU recurrence, one block per batch element ----------------
__global__ __launch_bounds__(768) void k_rec(const float* __restrict__ ehid,
                                             const _Float16* __restrict__ Whh0f,
                                             const _Float16* __restrict__ Wih1f,
                                             const _Float16* __restrict__ Whh1f,
                                             const float* __restrict__ b_ih,
                                             const float* __restrict__ b_hh,
                                             const float* __restrict__ gi0,
                                             _Float16* __restrict__ H1) {
  __shared__ float h0f[256], h1f[256];
  __shared__ __align__(16) _Float16 h0h[256], h1h[256];
  __shared__ float ghs[768], ga[768], gb[768];
  int b = blockIdx.x, tid = threadIdx.x;

  if (tid < 256) {
    // h0[l] = encoder_hidden[l] + encoder_hidden[2+l]
    float v0 = ehid[(size_t)(0 * 32 + b) * 256 + tid] + ehid[(size_t)(2 * 32 + b) * 256 + tid];
    float v1 = ehid[(size_t)(1 * 32 + b) * 256 + tid] + ehid[(size_t)(3 * 32 + b) * 256 + tid];
    h0f[tid] = v0; h0h[tid] = (_Float16)v0;
    h1f[tid] = v1; h1h[tid] = (_Float16)v1;
  }
  __syncthreads();

  for (int t = 0; t < 64; t++) {
    ghs[tid] = dotf16(Whh0f + (size_t)tid * 256, h0h, 32) + b_hh[tid];
    __syncthreads();
    if (tid < 256) {
      const float* gr = gi0 + (size_t)(t * 32 + b) * 768;
      float r = sigmf(gr[tid] + ghs[tid]);
      float z = sigmf(gr[tid + 256] + ghs[tid + 256]);
      float n = tanhfast(gr[tid + 512] + r * ghs[tid + 512]);
      float h = (1.f - z) * n + z * h0f[tid];
      h0f[tid] = h; h0h[tid] = (_Float16)h;
    }
    __syncthreads();
    ga[tid] = dotf16(Wih1f + (size_t)tid * 256, h0h, 32) + b_ih[768 + tid];
    gb[tid] = dotf16(Whh1f + (size_t)tid * 256, h1h, 32) + b_hh[768 + tid];
    __syncthreads();
    if (tid < 256) {
      float r = sigmf(ga[tid] + gb[tid]);
      float z = sigmf(ga[tid + 256] + gb[tid + 256]);
      float n = tanhfast(ga[tid + 512] + r * gb[tid + 512]);
      float h = (1.f - z) * n + z * h1f[tid];
      h1f[tid] = h; h1h[tid] = (_Float16)h;
      H1[(size_t)(t * 32 + b) * 256 + tid] = (_Float16)h;
    }
    __syncthreads();
  }
}

// ---------------- K3: attention + Ww projection per (t,b) ----------------
__global__ __launch_bounds__(256) void k_attn(const _Float16* __restrict__ H1,
                                              const _Float16* __restrict__ Waf,
                                              const float* __restrict__ ba,
                                              const _Float16* __restrict__ ench,
                                              const _Float16* __restrict__ Wwf,
                                              const float* __restrict__ bw,
                                              _Float16* __restrict__ Omat) {
  __shared__ __align__(16) _Float16 cat[768];   // [0:256)=h1, [256:768)=ctx
  __shared__ __align__(16) _Float16 qh[512];
  __shared__ float sc[64], wgt[64];
  int m = blockIdx.x, tid = threadIdx.x;
  int b = m & 31;

  cat[tid] = H1[(size_t)m * 256 + tid];
  __syncthreads();
#pragma unroll
  for (int p = 0; p < 2; p++) {
    int j = tid + p * 256;
    qh[j] = (_Float16)(dotf16(Waf + (size_t)j * 256, cat, 32) + ba[j]);
  }
  __syncthreads();
  if (tid < 64) sc[tid] = dotf16(ench + (size_t)(b * 64 + tid) * 512, qh, 64);
  __syncthreads();
  if (tid < 64) {  // softmax over 64 within wave 0
    float v = sc[tid], mx = v;
    for (int o = 32; o; o >>= 1) mx = fmaxf(mx, __shfl_xor(mx, o, 64));
    float e = __expf(v - mx), sm = e;
    for (int o = 32; o; o >>= 1) sm += __shfl_xor(sm, o, 64);
    wgt[tid] = e / sm;
  }
  __syncthreads();
#pragma unroll
  for (int p = 0; p < 2; p++) {
    int d = tid + p * 256;
    float acc = 0.f;
    const _Float16* ep = ench + (size_t)b * 64 * 512 + d;
#pragma unroll 8
    for (int s = 0; s < 64; s++) acc += wgt[s] * (float)ep[(size_t)s * 512];
    cat[256 + d] = (_Float16)acc;
  }
  __syncthreads();
#pragma unroll
  for (int p = 0; p < 3; p++) {
    int j = tid + p * 256;
    float o = dotf16(Wwf + (size_t)j * 768, cat, 96) + bw[j];
    Omat[(size_t)m * 768 + j] = (_Float16)fmaxf(o, 0.f);
  }
}

// ---------------- K4: logits = O @ Wo^T + bo, MFMA f16, permuted (b,t) store ----------------
__global__ __launch_bounds__(256) void k_gemm(const _Float16* __restrict__ O,
                                              const _Float16* __restrict__ Wo,
                                              const float* __restrict__ bo,
                                              float* __restrict__ out) {
  int idx = blockIdx.x;
  int mb = idx & 15;        // 16 m-blocks of 128 (M=2048)
  int nb = idx >> 4;        // 250 n-blocks of 128 (N=32000)
  int wave = threadIdx.x >> 6;
  int lane = threadIdx.x & 63;
  int m0 = mb * 128 + (wave >> 1) * 64;
  int n0 = nb * 128 + (wave & 1) * 64;
  int lm = lane & 15, lq = lane >> 4;

  f32x4 acc[4][4] = {};

  for (int kc = 0; kc < 768; kc += 32) {
    f16x8 a[4], bfr[4];
#pragma unroll
    for (int i = 0; i < 4; i++) {
      a[i]   = *(const f16x8*)(O  + (size_t)(m0 + 16 * i + lm) * 768 + kc + lq * 8);
      bfr[i] = *(const f16x8*)(Wo + (size_t)(n0 + 16 * i + lm) * 768 + kc + lq * 8);
    }
#pragma unroll
    for (int i = 0; i < 4; i++)
#pragma unroll
      for (int j = 0; j < 4; j++)
        acc[i][j] = __builtin_amdgcn_mfma_f32_16x16x32_f16(a[i], bfr[j], acc[i][j], 0, 0, 0);
  }

#pragma unroll
  for (int j = 0; j < 4; j++) {
    int n = n0 + 16 * j + lm;
    float bias = bo[n];
#pragma unroll
    for (int i = 0; i < 4; i++) {
#pragma unroll
      for (int r = 0; r < 4; r++) {
        int m = m0 + 16 * i + lq * 4 + r;   // m = t*32 + b
        int b = m & 31, t = m >> 5;
        out[(size_t)(b * 64 + t) * 32000 + n] = acc[i][j][r] + bias;
      }
    }
  }
}

extern "C" void kernel_launch(void* const* d_in, const int* in_sizes, int n_in,
                              void* d_out, int out_size, void* d_ws, size_t ws_size,
                              hipStream_t stream) {
  const float* enc  = (const float*)d_in[0];
  const float* ehid = (const float*)d_in[1];
  const int*   ow   = (const int*)d_in[2];
  const float* emb  = (const float*)d_in[3];
  const float* W_ih = (const float*)d_in[4];
  const float* W_hh = (const float*)d_in[5];
  const float* b_ih = (const float*)d_in[6];
  const float* b_hh = (const float*)d_in[7];
  const float* Wa   = (const float*)d_in[8];
  const float* ba   = (const float*)d_in[9];
  const float* Ww   = (const float*)d_in[10];
  const float* bw   = (const float*)d_in[11];
  const float* Wo   = (const float*)d_in[12];
  const float* bo   = (const float*)d_in[13];
  float* out = (float*)d_out;

  char* w = (char*)d_ws;
  _Float16* Wih0f = (_Float16*)(w + 0);
  _Float16* Whh0f = (_Float16*)(w + 393216);
  _Float16* Wih1f = (_Float16*)(w + 786432);
  _Float16* Whh1f = (_Float16*)(w + 1179648);
  _Float16* Waf   = (_Float16*)(w + 1572864);
  _Float16* Wwf   = (_Float16*)(w + 1835008);
  _Float16* ench  = (_Float16*)(w + 3014656);
  float*    gi0   = (float*)   (w + 5111808);
  _Float16* H1    = (_Float16*)(w + 11403264);
  _Float16* Omat  = (_Float16*)(w + 12451840);
  _Float16* Wof   = (_Float16*)(w + 15597568);
  // total ws use: ~64.75 MB

  k_cvt<<<256,  256, 0, stream>>>(W_ih,           Wih0f, 196608);
  k_cvt<<<256,  256, 0, stream>>>(W_hh,           Whh0f, 196608);
  k_cvt<<<256,  256, 0, stream>>>(W_ih + 196608,  Wih1f, 196608);
  k_cvt<<<256,  256, 0, stream>>>(W_hh + 196608,  Whh1f, 196608);
  k_cvt<<<256,  256, 0, stream>>>(Wa,             Waf,   131072);
  k_cvt<<<512,  256, 0, stream>>>(Ww,             Wwf,   589824);
  k_cvt<<<512,  256, 0, stream>>>(enc,            ench,  1048576);
  k_cvt<<<2048, 256, 0, stream>>>(Wo,             Wof,   24576000);

  k_gi0 <<<2048, 256, 0, stream>>>(ow, emb, Wih0f, b_ih, gi0);
  k_rec <<<32,   768, 0, stream>>>(ehid, Whh0f, Wih1f, Whh1f, b_ih, b_hh, gi0, H1);
  k_attn<<<2048, 256, 0, stream>>>(H1, Waf, ba, ench, Wwf, bw, Omat);
  k_gemm<<<4000, 256, 0, stream>>>(Omat, Wof, bo, out);
}